// Round 1
// baseline (136.185 us; speedup 1.0000x reference)
//
#include <hip/hip_runtime.h>
#include <stdint.h>

#define NM 2048

typedef _Float16 f16;
typedef __attribute__((ext_vector_type(8))) _Float16 half8;
typedef __attribute__((ext_vector_type(4))) float float4v;

// ---------------------------------------------------------------------------
// X = A - A^T  (f16).  |X| <~ 0.1 so f16 abs err < 4e-5/entry.
// ---------------------------------------------------------------------------
__global__ void skew_f16_kernel(const float* __restrict__ A, f16* __restrict__ X) {
    __shared__ float t[32][33];
    const int bx = blockIdx.x * 32, by = blockIdx.y * 32;
    const int tx = threadIdx.x, ty = threadIdx.y;
    #pragma unroll
    for (int r = 0; r < 32; r += 8)
        t[ty + r][tx] = A[(size_t)(bx + ty + r) * NM + by + tx];
    __syncthreads();
    #pragma unroll
    for (int r = 0; r < 32; r += 8) {
        const int i = by + ty + r, j = bx + tx;
        X[(size_t)i * NM + j] = (f16)(A[(size_t)i * NM + j] - t[tx][ty + r]);
    }
}

// ---------------------------------------------------------------------------
// 256x256-tile, BK=64, 8-wave (2x4, wave tile 128x64), 8-phase counted-vmcnt
// GEMM (T2 swizzle + T3/T4 phase pipeline + T5 setprio), split-K=4.
// Block (tile, s) computes  P[s] = A_tile * BT_tile^T  over k in [s*512,+512),
// written as an f16 partial plane (no fused epilogue; reduce kernels handle it).
//
// Staging units = MFMA stripe sets:
//   A-m0 = A rows {0..63,128..191}, A-m1 = {64..127,192..255}  (per tile)
//   B-n0 = B rows {0..31,64..95,128..159,192..223}, B-n1 = the other stripes
// Quadrant order per K-tile: (m0,n0),(m0,n1),(m1,n1),(m1,n0).
// Issue slots (unit of tile T): A-m0@(T-2,ph3), B-n1@(T-2,ph4),
//                               A-m1@(T-1,ph1), B-n0@(T-1,ph2)
// -> every unit is staged strictly after the phase in which its previous
//    occupant was last ds_read (certified by lgkmcnt(0) before each phase-
//    closing s_barrier), and a single s_waitcnt vmcnt(6) per K-tile (at ph1)
//    certifies the whole tile: exactly 3 units (6 loads) are newer by
//    construction.  Loads never drain to 0 in the main loop.
// LDS: 2 x 64 KB K-tile buffers = 128 KB (dynamic), 1 block/CU, 2 waves/SIMD.
// ---------------------------------------------------------------------------
#define STAGE_UNIT(kt, u)                                                         \
    {                                                                             \
        f16* _b = lds + ((kt) & 1) * BUFH;                                        \
        const f16* _g = gsrc[u] + (kt) * 64;                                      \
        __builtin_amdgcn_global_load_lds(                                         \
            (const __attribute__((address_space(1))) void*)_g,                    \
            (__attribute__((address_space(3))) void*)(uintptr_t)(_b + loff[u]),   \
            16, 0, 0);                                                            \
        __builtin_amdgcn_global_load_lds(                                         \
            (const __attribute__((address_space(1))) void*)(_g + (size_t)128 * NM), \
            (__attribute__((address_space(3))) void*)(uintptr_t)(_b + loff[u] + 8192), \
            16, 0, 0);                                                            \
    }

#define MFMA_QUAD(MH, NH)                                                         \
    __builtin_amdgcn_s_setprio(1);                                                \
    _Pragma("unroll")                                                             \
    for (int r = 0; r < 4; ++r)                                                   \
        _Pragma("unroll")                                                         \
        for (int c = 0; c < 2; ++c)                                               \
            _Pragma("unroll")                                                     \
            for (int kk = 0; kk < 2; ++kk)                                        \
                acc[MH][NH][r][c] = __builtin_amdgcn_mfma_f32_16x16x32_f16(       \
                    ah[r][kk], bh[c][kk], acc[MH][NH][r][c], 0, 0, 0);            \
    __builtin_amdgcn_s_setprio(0);                                                \
    asm volatile("s_waitcnt lgkmcnt(0)" ::: "memory");                            \
    asm volatile("s_barrier" ::: "memory");

__global__ __launch_bounds__(512, 2) void gemm8_kernel(
    const f16* __restrict__ Ap, const f16* __restrict__ BTp, f16* __restrict__ Pp)
{
    extern __shared__ __align__(16) f16 lds[];
    constexpr int PLB  = 16384;   // B plane base (halfs) within a buffer
    constexpr int BUFH = 32768;   // halfs per K-tile buffer (64 KB)
    constexpr int NT   = 8;       // K-tiles per block (512 / 64)

    const int tid  = threadIdx.x;
    const int wave = tid >> 6, lane = tid & 63;
    const int wr = wave >> 2, wc = wave & 3;   // 2 x 4 waves, wave tile 128x64
    const int l15 = lane & 15, qq = lane >> 4;

    // XCD-aware decomposition: xcd -> (k-slice, row-half); 32 blocks per XCD
    // cover 4x8 tiles of one k-slice half: ~3 MB L2 footprint per XCD.
    const int bid = blockIdx.x;
    const int xcd = bid & 7, li = bid >> 3;
    const int sk   = xcd >> 1;                   // split-K index 0..3
    const int trow = (xcd & 1) * 4 + (li >> 3);  // 0..7
    const int tcol = li & 7;                     // 0..7
    const int rowBase = trow * 256, colBase = tcol * 256;
    const int kBase = sk * 512;

    // Staging bases: per unit, load 0 of 2 (load 1 = +128 rows, same swizzle).
    // Row m, physical chunk sp holds logical k-chunk sl = sp ^ (m&7).
    const f16* gsrc[4];
    int loff[4];
    {
        const int m = tid >> 3, sp = tid & 7;       // m in [0,64)
        const int rA0 = m;
        const int rA1 = 64 + m;
        const int rB0 = (m & 31) + ((m >> 5) << 6);
        const int rB1 = 32 + rB0;
        gsrc[0] = Ap  + (size_t)(rowBase + rA0) * NM + kBase + (sp ^ (rA0 & 7)) * 8;
        gsrc[1] = Ap  + (size_t)(rowBase + rA1) * NM + kBase + (sp ^ (rA1 & 7)) * 8;
        gsrc[2] = BTp + (size_t)(colBase + rB0) * NM + kBase + (sp ^ (rB0 & 7)) * 8;
        gsrc[3] = BTp + (size_t)(colBase + rB1) * NM + kBase + (sp ^ (rB1 & 7)) * 8;
        loff[0] = (rA0 * 8 + sp) * 8;
        loff[1] = (rA1 * 8 + sp) * 8;
        loff[2] = PLB + (rB0 * 8 + sp) * 8;
        loff[3] = PLB + (rB1 * 8 + sp) * 8;
    }

    // LDS fragment offsets (m-half 0 / n-half 0; +4096/+2048 halfs for half 1)
    int offA[4][2], offB[2][2];
    #pragma unroll
    for (int r = 0; r < 4; ++r)
        #pragma unroll
        for (int kk = 0; kk < 2; ++kk) {
            const int row = wr * 128 + r * 16 + l15;
            offA[r][kk] = (row * 8 + ((kk * 4 + qq) ^ (row & 7))) * 8;
        }
    #pragma unroll
    for (int c = 0; c < 2; ++c)
        #pragma unroll
        for (int kk = 0; kk < 2; ++kk) {
            const int row = wc * 64 + c * 16 + l15;
            offB[c][kk] = PLB + (row * 8 + ((kk * 4 + qq) ^ (row & 7))) * 8;
        }

    float4v acc[2][2][4][2];
    #pragma unroll
    for (int mh = 0; mh < 2; ++mh)
        #pragma unroll
        for (int nh = 0; nh < 2; ++nh)
            #pragma unroll
            for (int r = 0; r < 4; ++r)
                #pragma unroll
                for (int c = 0; c < 2; ++c)
                    acc[mh][nh][r][c] = (float4v){0.f, 0.f, 0.f, 0.f};

    half8 ah[4][2], bh[2][2];

    // Prologue: tile0 {A-m0, B-n1, A-m1, B-n0}, tile1 {A-m0, B-n1} = 6 units.
    STAGE_UNIT(0, 0)
    STAGE_UNIT(0, 3)
    STAGE_UNIT(0, 1)
    STAGE_UNIT(0, 2)
    STAGE_UNIT(1, 0)
    STAGE_UNIT(1, 3)

    #pragma unroll
    for (int t = 0; t < NT; ++t) {
        const f16* base = lds + (t & 1) * BUFH;

        // ---- phase 1: quadrant (m0,n0); stage A-m1(t+1) ----
        if (t + 1 < NT) STAGE_UNIT(t + 1, 1)
        if (t == NT - 1) { asm volatile("s_waitcnt vmcnt(0)" ::: "memory"); }
        else             { asm volatile("s_waitcnt vmcnt(6)" ::: "memory"); }
        asm volatile("s_barrier" ::: "memory");
        #pragma unroll
        for (int r = 0; r < 4; ++r)
            #pragma unroll
            for (int kk = 0; kk < 2; ++kk)
                ah[r][kk] = *(const half8*)&base[offA[r][kk]];
        #pragma unroll
        for (int c = 0; c < 2; ++c)
            #pragma unroll
            for (int kk = 0; kk < 2; ++kk)
                bh[c][kk] = *(const half8*)&base[offB[c][kk]];
        MFMA_QUAD(0, 0)

        // ---- phase 2: quadrant (m0,n1); stage B-n0(t+1) ----
        if (t + 1 < NT) STAGE_UNIT(t + 1, 2)
        asm volatile("s_barrier" ::: "memory");
        #pragma unroll
        for (int c = 0; c < 2; ++c)
            #pragma unroll
            for (int kk = 0; kk < 2; ++kk)
                bh[c][kk] = *(const half8*)&base[offB[c][kk] + 2048];
        MFMA_QUAD(0, 1)

        // ---- phase 3: quadrant (m1,n1); stage A-m0(t+2) ----
        if (t + 2 < NT) STAGE_UNIT(t + 2, 0)
        asm volatile("s_barrier" ::: "memory");
        #pragma unroll
        for (int r = 0; r < 4; ++r)
            #pragma unroll
            for (int kk = 0; kk < 2; ++kk)
                ah[r][kk] = *(const half8*)&base[offA[r][kk] + 4096];
        MFMA_QUAD(1, 1)

        // ---- phase 4: quadrant (m1,n0); stage B-n1(t+2) ----
        if (t + 2 < NT) STAGE_UNIT(t + 2, 3)
        asm volatile("s_barrier" ::: "memory");
        #pragma unroll
        for (int c = 0; c < 2; ++c)
            #pragma unroll
            for (int kk = 0; kk < 2; ++kk)
                bh[c][kk] = *(const half8*)&base[offB[c][kk]];
        MFMA_QUAD(1, 0)
    }

    // Epilogue: write f16 partial plane.  C/D layout: col=lane&15, row=qq*4+g.
    f16* dst = Pp + (size_t)sk * NM * NM;
    #pragma unroll
    for (int mh = 0; mh < 2; ++mh)
        #pragma unroll
        for (int nh = 0; nh < 2; ++nh)
            #pragma unroll
            for (int r = 0; r < 4; ++r)
                #pragma unroll
                for (int c = 0; c < 2; ++c)
                    #pragma unroll
                    for (int g = 0; g < 4; ++g) {
                        const int row = rowBase + wr * 128 + mh * 64 + r * 16 + qq * 4 + g;
                        const int col = colBase + wc * 64 + nh * 32 + c * 16 + l15;
                        dst[(size_t)row * NM + col] = (f16)acc[mh][nh][r][c][g];
                    }
}

// ---------------------------------------------------------------------------
// reduce0: X2 = -(sum of 4 partials of X*X^T);  CT = 256*C^T where
//          C = X/6 + X2/24  ->  CT[i,j] = 256*(X2[i,j]/24 - X[i,j]/6).
// ---------------------------------------------------------------------------
__global__ __launch_bounds__(256) void reduce0_kernel(
    const f16* __restrict__ P, const f16* __restrict__ X,
    f16* __restrict__ X2, f16* __restrict__ CT)
{
    const size_t NN = (size_t)NM * NM;
    const size_t i = ((size_t)blockIdx.x * 256 + threadIdx.x) * 8;
    const half8 p0 = *(const half8*)(P + i);
    const half8 p1 = *(const half8*)(P + NN + i);
    const half8 p2 = *(const half8*)(P + 2 * NN + i);
    const half8 p3 = *(const half8*)(P + 3 * NN + i);
    const half8 xv = *(const half8*)(X + i);
    half8 x2v, ctv;
    #pragma unroll
    for (int j = 0; j < 8; ++j) {
        const float s  = (float)p0[j] + (float)p1[j] + (float)p2[j] + (float)p3[j];
        const float x2 = -s;
        const float x  = (float)xv[j];
        x2v[j] = (f16)x2;
        ctv[j] = (f16)(x2 * (256.0f / 24.0f) - x * (256.0f / 6.0f));
    }
    *(half8*)(X2 + i) = x2v;
    *(half8*)(CT + i) = ctv;
}

// ---------------------------------------------------------------------------
// reduce1: OUT = I + X + X2/2 + (sum of 4 partials of 256*X2*C)/256   (fp32)
// ---------------------------------------------------------------------------
__global__ __launch_bounds__(256) void reduce1_kernel(
    const f16* __restrict__ P, const f16* __restrict__ X,
    const f16* __restrict__ X2, float* __restrict__ OUT)
{
    const size_t NN = (size_t)NM * NM;
    const size_t i = ((size_t)blockIdx.x * 256 + threadIdx.x) * 8;
    const half8 p0  = *(const half8*)(P + i);
    const half8 p1  = *(const half8*)(P + NN + i);
    const half8 p2  = *(const half8*)(P + 2 * NN + i);
    const half8 p3  = *(const half8*)(P + 3 * NN + i);
    const half8 xv  = *(const half8*)(X + i);
    const half8 x2v = *(const half8*)(X2 + i);
    float o[8];
    #pragma unroll
    for (int j = 0; j < 8; ++j) {
        const float q = (float)p0[j] + (float)p1[j] + (float)p2[j] + (float)p3[j];
        o[j] = (float)xv[j] + 0.5f * (float)x2v[j] + q * (1.0f / 256.0f);
    }
    const int row = (int)(i >> 11), col0 = (int)(i & 2047);
    if (row >= col0 && row < col0 + 8) o[row - col0] += 1.0f;
    *(float4v*)(OUT + i)     = (float4v){o[0], o[1], o[2], o[3]};
    *(float4v*)(OUT + i + 4) = (float4v){o[4], o[5], o[6], o[7]};
}

// ---------------------------------------------------------------------------
// exp(S) ~= T4(S) = I + X + X2/2 + X2*(X/6 + X2/24),  X = A - A^T.
// ws: X, X2, CT + 4 f16 partial planes = 7 * 8.4 MB = 58.7 MB.
// ---------------------------------------------------------------------------
extern "C" void kernel_launch(void* const* d_in, const int* in_sizes, int n_in,
                              void* d_out, int out_size, void* d_ws, size_t ws_size,
                              hipStream_t stream) {
    const float* A = (const float*)d_in[0];
    float* out = (float*)d_out;
    const size_t NN = (size_t)NM * NM;

    f16* X  = (f16*)d_ws;
    f16* X2 = X + NN;
    f16* CT = X2 + NN;
    f16* P  = CT + NN;   // 4 partial planes

    static int attr_done = 0;
    if (!attr_done) {
        hipFuncSetAttribute((const void*)gemm8_kernel,
                            hipFuncAttributeMaxDynamicSharedMemorySize, 131072);
        attr_done = 1;
    }

    dim3 tb(32, 8), tg(NM / 32, NM / 32);
    // 1) X = A - A^T
    skew_f16_kernel<<<tg, tb, 0, stream>>>(A, X);
    // 2) partials of X*X^T (= -X2)
    gemm8_kernel<<<256, 512, 131072, stream>>>(X, X, P);
    // 3) X2, CT
    reduce0_kernel<<<2048, 256, 0, stream>>>(P, X, X2, CT);
    // 4) partials of X2*CT^T (= 256*X2*C)
    gemm8_kernel<<<256, 512, 131072, stream>>>(X2, CT, P);
    // 5) OUT = I + X + X2/2 + v/256
    reduce1_kernel<<<2048, 256, 0, stream>>>(P, X, X2, out);
}

// Round 3
// 135.824 us; speedup vs baseline: 1.0027x; 1.0027x over previous
//
#include <hip/hip_runtime.h>
#include <stdint.h>

#define NM 2048

typedef _Float16 f16;
typedef __attribute__((ext_vector_type(8))) _Float16 half8;
typedef __attribute__((ext_vector_type(4))) float float4v;

// ---------------------------------------------------------------------------
// X = A - A^T  (f16).  |X| <~ 0.1 so f16 abs err < 4e-5/entry.
// ---------------------------------------------------------------------------
__global__ void skew_f16_kernel(const float* __restrict__ A, f16* __restrict__ X) {
    __shared__ float t[32][33];
    const int bx = blockIdx.x * 32, by = blockIdx.y * 32;
    const int tx = threadIdx.x, ty = threadIdx.y;
    #pragma unroll
    for (int r = 0; r < 32; r += 8)
        t[ty + r][tx] = A[(size_t)(bx + ty + r) * NM + by + tx];
    __syncthreads();
    #pragma unroll
    for (int r = 0; r < 32; r += 8) {
        const int i = by + ty + r, j = bx + tx;
        X[(size_t)i * NM + j] = (f16)(A[(size_t)i * NM + j] - t[tx][ty + r]);
    }
}

// ---------------------------------------------------------------------------
// 256x256-tile, BK=64, 8-wave (2x4, wave tile 128x64) 8-phase counted-vmcnt
// GEMM, split-K=4 -> 256 blocks (1/CU).
//
// CERTIFICATION RULE (the round-2 bug): vmcnt is PER-WAVE, so a buffer may
// be read only after {every wave's own vmcnt wait for that buffer} -> barrier.
// Hence the per-tile wait sits at the END of the previous tile's p4, between
// the read-certifying lgkmcnt(0) and the closing s_barrier; tile T's p1
// ds_reads are issued after that barrier.
//
// Units (per tile): u0=A rows{0..63,128..191}, u1=A{64..127,192..255},
// u2=B{0..31,64..95,...}, u3=B{32..63,96..127,...}.  Quadrants
// (m0,n0),(m0,n1),(m1,n1),(m1,n0).  Last-read phase: u0:p1, u2:p4(re-read),
// u3:p2, u1:p3.  Stage slots for tile T: u1(T+1)@T.p1, u2(T+1)@T.p2 (other
// buffer), u0(T+2)@T.p3, u3(T+2)@T.p4 (current buffer, after their last
// reads' lgkmcnt(0)+barrier).  End-of-tile wait: outstanding = 8 this-tile
// stages + 4 older (T+1's u0,u3); need T+1's 8 oldest -> vmcnt(4); newer:
// u0,u3 of T+2 (4 loads).  vmcnt never drains to 0 until tile 6's end.
// K-tile pairs per iteration (#pragma unroll 1) keep buffer bases
// compile-time; tiles 6,7 peeled for the staging tail.
// LDS: 2 x 64 KB buffers = 128 KB, 1 block/CU, 2 waves/SIMD.
// ---------------------------------------------------------------------------
#define BARRIER asm volatile("s_barrier" ::: "memory")
#define LG0     asm volatile("s_waitcnt lgkmcnt(0)" ::: "memory")
#define W4      asm volatile("s_waitcnt vmcnt(4)" ::: "memory")
#define W0      asm volatile("s_waitcnt vmcnt(0)" ::: "memory")
#define NOST    ((void)0)

#define STAGE_U(u, dst)                                                       \
    do {                                                                      \
        __builtin_amdgcn_global_load_lds(                                     \
            (const __attribute__((address_space(1))) void*)gsrc[u],           \
            (__attribute__((address_space(3))) void*)(uintptr_t)((dst) + loff[u]), \
            16, 0, 0);                                                        \
        __builtin_amdgcn_global_load_lds(                                     \
            (const __attribute__((address_space(1))) void*)(gsrc[u] + (size_t)128 * NM), \
            (__attribute__((address_space(3))) void*)(uintptr_t)((dst) + loff[u] + 8192), \
            16, 0, 0);                                                        \
        gsrc[u] += 64;                                                        \
    } while (0)

#define RD_A(BB, HOFF)                                                        \
    { _Pragma("unroll")                                                       \
      for (int r_ = 0; r_ < 4; ++r_)                                          \
        _Pragma("unroll")                                                     \
        for (int k_ = 0; k_ < 2; ++k_)                                        \
            ah[r_][k_] = *(const half8*)&(BB)[offA[r_][k_] + (HOFF)]; }

#define RD_B(BB, HOFF)                                                        \
    { _Pragma("unroll")                                                       \
      for (int c_ = 0; c_ < 2; ++c_)                                          \
        _Pragma("unroll")                                                     \
        for (int k_ = 0; k_ < 2; ++k_)                                        \
            bh[c_][k_] = *(const half8*)&(BB)[offB[c_][k_] + (HOFF)]; }

#define MQ(MH, NH)                                                            \
    __builtin_amdgcn_s_setprio(1);                                            \
    _Pragma("unroll")                                                         \
    for (int r_ = 0; r_ < 4; ++r_)                                            \
        _Pragma("unroll")                                                     \
        for (int c_ = 0; c_ < 2; ++c_)                                        \
            _Pragma("unroll")                                                 \
            for (int k_ = 0; k_ < 2; ++k_)                                    \
                acc[MH][NH][r_][c_] = __builtin_amdgcn_mfma_f32_16x16x32_f16( \
                    ah[r_][k_], bh[c_][k_], acc[MH][NH][r_][c_], 0, 0, 0);    \
    __builtin_amdgcn_s_setprio(0);

// One K-tile (4 phases).  This tile's buffer was certified by the previous
// tile's ENDW + barrier.  ENDW certifies the NEXT tile's buffer.
#define TILE_BLOCK(CUR, S1, S2, S3, S4, ENDW)                                 \
    {                                                                         \
        const f16* Bb = (CUR);                                                \
        /* p1: (m0,n0) */                                                     \
        RD_A(Bb, 0); RD_B(Bb, 0);                                             \
        S1;                                                                   \
        BARRIER; LG0;                                                         \
        MQ(0, 0);                                                             \
        LG0; BARRIER;                                                         \
        /* p2: (m0,n1) */                                                     \
        RD_B(Bb, 2048);                                                       \
        S2;                                                                   \
        BARRIER; LG0;                                                         \
        MQ(0, 1);                                                             \
        LG0; BARRIER;                                                         \
        /* p3: (m1,n1) */                                                     \
        RD_A(Bb, 4096);                                                       \
        S3;                                                                   \
        BARRIER; LG0;                                                         \
        MQ(1, 1);                                                             \
        LG0; BARRIER;                                                         \
        /* p4: (m1,n0) */                                                     \
        RD_B(Bb, 0);                                                          \
        S4;                                                                   \
        BARRIER; LG0;                                                         \
        MQ(1, 0);                                                             \
        LG0; ENDW; BARRIER;                                                   \
    }

__global__ __launch_bounds__(512, 2) void gemm8_kernel(
    const f16* __restrict__ Ap, const f16* __restrict__ BTp, f16* __restrict__ Pp)
{
    extern __shared__ __align__(16) f16 lds[];
    constexpr int PLB  = 16384;   // B plane base (halfs) within a buffer
    constexpr int BUFH = 32768;   // halfs per K-tile buffer (64 KB)

    const int tid  = threadIdx.x;
    const int wave = tid >> 6, lane = tid & 63;
    const int wr = wave >> 2, wc = wave & 3;   // 2 x 4 waves, wave tile 128x64
    const int l15 = lane & 15, qq = lane >> 4;

    // XCD-aware decomposition: xcd -> (k-slice, row-half); 32 blocks per XCD
    // cover 4x8 tiles of one k-slice half (~3 MB L2 footprint per XCD).
    const int bid = blockIdx.x;
    const int xcd = bid & 7, li = bid >> 3;
    const int sk   = xcd >> 1;                   // split-K index 0..3
    const int trow = (xcd & 1) * 4 + (li >> 3);  // 0..7
    const int tcol = li & 7;                     // 0..7
    const int rowBase = trow * 256, colBase = tcol * 256;
    const int kBase = sk * 512;

    // Staging bases (load 0 of 2; load 1 = +128 rows, same swizzle).
    // Row m, physical chunk sp holds logical k-chunk sl = sp ^ (m&7).
    const f16* gsrc[4];
    int loff[4];
    {
        const int m = tid >> 3, sp = tid & 7;       // m in [0,64)
        const int rA0 = m;
        const int rA1 = 64 + m;
        const int rB0 = (m & 31) + ((m >> 5) << 6);
        const int rB1 = 32 + rB0;
        gsrc[0] = Ap  + (size_t)(rowBase + rA0) * NM + kBase + (sp ^ (rA0 & 7)) * 8;
        gsrc[1] = Ap  + (size_t)(rowBase + rA1) * NM + kBase + (sp ^ (rA1 & 7)) * 8;
        gsrc[2] = BTp + (size_t)(colBase + rB0) * NM + kBase + (sp ^ (rB0 & 7)) * 8;
        gsrc[3] = BTp + (size_t)(colBase + rB1) * NM + kBase + (sp ^ (rB1 & 7)) * 8;
        loff[0] = (rA0 * 8 + sp) * 8;
        loff[1] = (rA1 * 8 + sp) * 8;
        loff[2] = PLB + (rB0 * 8 + sp) * 8;
        loff[3] = PLB + (rB1 * 8 + sp) * 8;
    }

    // LDS fragment offsets (m-half 0 / n-half 0; +4096/+2048 halfs for half 1)
    int offA[4][2], offB[2][2];
    #pragma unroll
    for (int r = 0; r < 4; ++r)
        #pragma unroll
        for (int kk = 0; kk < 2; ++kk) {
            const int row = wr * 128 + r * 16 + l15;
            offA[r][kk] = (row * 8 + ((kk * 4 + qq) ^ (row & 7))) * 8;
        }
    #pragma unroll
    for (int c = 0; c < 2; ++c)
        #pragma unroll
        for (int kk = 0; kk < 2; ++kk) {
            const int row = wc * 64 + c * 16 + l15;
            offB[c][kk] = PLB + (row * 8 + ((kk * 4 + qq) ^ (row & 7))) * 8;
        }

    float4v acc[2][2][4][2];
    #pragma unroll
    for (int mh = 0; mh < 2; ++mh)
        #pragma unroll
        for (int nh = 0; nh < 2; ++nh)
            #pragma unroll
            for (int r = 0; r < 4; ++r)
                #pragma unroll
                for (int c = 0; c < 2; ++c)
                    acc[mh][nh][r][c] = (float4v){0.f, 0.f, 0.f, 0.f};

    half8 ah[4][2], bh[2][2];

    f16* B0 = lds;
    f16* B1 = lds + BUFH;

    // Prologue: tile0 all units, then u0(t1), u3(t1); certify tile 0:
    // own-wave vmcnt(4) (completes the 8 tile-0 loads) then barrier.
    STAGE_U(0, B0); STAGE_U(1, B0); STAGE_U(2, B0); STAGE_U(3, B0);
    STAGE_U(0, B1); STAGE_U(3, B1);
    W4; BARRIER;

    // Tiles 0..5 in pairs.  Tile T stages u1,u2 -> other buffer (tile T+1),
    // u0,u3 -> current buffer (tile T+2); end wait vmcnt(4) certifies T+1.
    #pragma unroll 1
    for (int i = 0; i < 3; ++i) {
        TILE_BLOCK(B0, STAGE_U(1, B1), STAGE_U(2, B1), STAGE_U(0, B0), STAGE_U(3, B0), W4)
        TILE_BLOCK(B1, STAGE_U(1, B0), STAGE_U(2, B0), STAGE_U(0, B1), STAGE_U(3, B1), W4)
    }
    // Peeled tail: tile 6 stages only u1,u2 of tile 7, ends with vmcnt(0)
    // (no newer loads); tile 7 stages nothing.
    TILE_BLOCK(B0, STAGE_U(1, B1), STAGE_U(2, B1), NOST, NOST, W0)
    TILE_BLOCK(B1, NOST, NOST, NOST, NOST, NOST)

    // Epilogue: write f16 partial plane.  C/D layout: col=lane&15, row=qq*4+g.
    f16* dst = Pp + (size_t)sk * NM * NM;
    #pragma unroll
    for (int mh = 0; mh < 2; ++mh)
        #pragma unroll
        for (int nh = 0; nh < 2; ++nh)
            #pragma unroll
            for (int r = 0; r < 4; ++r)
                #pragma unroll
                for (int c = 0; c < 2; ++c)
                    #pragma unroll
                    for (int g = 0; g < 4; ++g) {
                        const int row = rowBase + wr * 128 + mh * 64 + r * 16 + qq * 4 + g;
                        const int col = colBase + wc * 64 + nh * 32 + c * 16 + l15;
                        dst[(size_t)row * NM + col] = (f16)acc[mh][nh][r][c][g];
                    }
}

// ---------------------------------------------------------------------------
// reduce0: X2 = -(sum of 4 partials of X*X^T);  CT = 256*C^T where
//          C = X/6 + X2/24  ->  CT[i,j] = 256*(X2[i,j]/24 - X[i,j]/6).
// ---------------------------------------------------------------------------
__global__ __launch_bounds__(256) void reduce0_kernel(
    const f16* __restrict__ P, const f16* __restrict__ X,
    f16* __restrict__ X2, f16* __restrict__ CT)
{
    const size_t NN = (size_t)NM * NM;
    const size_t i = ((size_t)blockIdx.x * 256 + threadIdx.x) * 8;
    const half8 p0 = *(const half8*)(P + i);
    const half8 p1 = *(const half8*)(P + NN + i);
    const half8 p2 = *(const half8*)(P + 2 * NN + i);
    const half8 p3 = *(const half8*)(P + 3 * NN + i);
    const half8 xv = *(const half8*)(X + i);
    half8 x2v, ctv;
    #pragma unroll
    for (int j = 0; j < 8; ++j) {
        const float s  = (float)p0[j] + (float)p1[j] + (float)p2[j] + (float)p3[j];
        const float x2 = -s;
        const float x  = (float)xv[j];
        x2v[j] = (f16)x2;
        ctv[j] = (f16)(x2 * (256.0f / 24.0f) - x * (256.0f / 6.0f));
    }
    *(half8*)(X2 + i) = x2v;
    *(half8*)(CT + i) = ctv;
}

// ---------------------------------------------------------------------------
// reduce1: OUT = I + X + X2/2 + (sum of 4 partials of 256*X2*C)/256   (fp32)
// ---------------------------------------------------------------------------
__global__ __launch_bounds__(256) void reduce1_kernel(
    const f16* __restrict__ P, const f16* __restrict__ X,
    const f16* __restrict__ X2, float* __restrict__ OUT)
{
    const size_t NN = (size_t)NM * NM;
    const size_t i = ((size_t)blockIdx.x * 256 + threadIdx.x) * 8;
    const half8 p0  = *(const half8*)(P + i);
    const half8 p1  = *(const half8*)(P + NN + i);
    const half8 p2  = *(const half8*)(P + 2 * NN + i);
    const half8 p3  = *(const half8*)(P + 3 * NN + i);
    const half8 xv  = *(const half8*)(X + i);
    const half8 x2v = *(const half8*)(X2 + i);
    float o[8];
    #pragma unroll
    for (int j = 0; j < 8; ++j) {
        const float q = (float)p0[j] + (float)p1[j] + (float)p2[j] + (float)p3[j];
        o[j] = (float)xv[j] + 0.5f * (float)x2v[j] + q * (1.0f / 256.0f);
    }
    const int row = (int)(i >> 11), col0 = (int)(i & 2047);
    if (row >= col0 && row < col0 + 8) o[row - col0] += 1.0f;
    *(float4v*)(OUT + i)     = (float4v){o[0], o[1], o[2], o[3]};
    *(float4v*)(OUT + i + 4) = (float4v){o[4], o[5], o[6], o[7]};
}

// ---------------------------------------------------------------------------
// exp(S) ~= T4(S) = I + X + X2/2 + X2*(X/6 + X2/24),  X = A - A^T.
// ws: X, X2, CT + 4 f16 partial planes = 7 * 8.4 MB = 58.7 MB.
// ---------------------------------------------------------------------------
extern "C" void kernel_launch(void* const* d_in, const int* in_sizes, int n_in,
                              void* d_out, int out_size, void* d_ws, size_t ws_size,
                              hipStream_t stream) {
    const float* A = (const float*)d_in[0];
    float* out = (float*)d_out;
    const size_t NN = (size_t)NM * NM;

    f16* X  = (f16*)d_ws;
    f16* X2 = X + NN;
    f16* CT = X2 + NN;
    f16* P  = CT + NN;   // 4 partial planes

    static int attr_done = 0;
    if (!attr_done) {
        hipFuncSetAttribute((const void*)gemm8_kernel,
                            hipFuncAttributeMaxDynamicSharedMemorySize, 131072);
        attr_done = 1;
    }

    dim3 tb(32, 8), tg(NM / 32, NM / 32);
    // 1) X = A - A^T
    skew_f16_kernel<<<tg, tb, 0, stream>>>(A, X);
    // 2) partials of X*X^T (= -X2)
    gemm8_kernel<<<256, 512, 131072, stream>>>(X, X, P);
    // 3) X2, CT
    reduce0_kernel<<<2048, 256, 0, stream>>>(P, X, X2, CT);
    // 4) partials of X2*CT^T (= 256*X2*C)
    gemm8_kernel<<<256, 512, 131072, stream>>>(X2, CT, P);
    // 5) OUT = I + X + X2/2 + v/256
    reduce1_kernel<<<2048, 256, 0, stream>>>(P, X, X2, out);
}